// Round 9
// baseline (395.809 us; speedup 1.0000x reference)
//
#include <hip/hip_runtime.h>

typedef __bf16  bf16x4 __attribute__((ext_vector_type(4)));
typedef __bf16  bf16x8 __attribute__((ext_vector_type(8)));
typedef float   f32x4  __attribute__((ext_vector_type(4)));
typedef unsigned int u32;

constexpr int BM = 128, BN = 128, BK = 32;

// async global->LDS, 16B per lane. LDS dest is wave-uniform base + lane*16.
__device__ __forceinline__ void async_cp16(const __bf16* g, __bf16* lds) {
    __builtin_amdgcn_global_load_lds(
        (const __attribute__((address_space(1))) u32*)g,
        (__attribute__((address_space(3))) u32*)lds, 16, 0, 0);
}

// swizzled LDS offset (in shorts) of (row, 16B-slot q) for 32-wide rows
__device__ __forceinline__ int swz(int row, int q) {
    return row * BK + (((q + (row >> 1)) & 3) << 3);
}

// ---------------------------------------------------------------------------
// NT GEMM (128x128xBK32), LDS double-buffered: stage(t+1) issued before the
// compute of tile t, ONE barrier per K-step -> DMA latency hides under MFMA.
// EPI: 1 = bf16 store, 2 = +bias,leakyRelu -> bf16,
//      3 = bf16 partial at C0 + chunk*pstrideB,
//      4 = bf16 split across C0/C1/C2 by col/256
// blockIdx.z batches independent (A,B,C) triples via sA/sB/sC strides.
// ---------------------------------------------------------------------------
template<int EPI>
__launch_bounds__(256)
__global__ void gemm_nt(const __bf16* __restrict__ Aall, const __bf16* __restrict__ Ball,
                        const float* __restrict__ bias,
                        void* __restrict__ C0, void* __restrict__ C1, void* __restrict__ C2,
                        int N, int K, long ldb, long sA, long sB, long sC,
                        int nTx, int klen, long pstrideB)
{
    const int bx = blockIdx.x;
    const int chunk = bx / nTx;
    const int n0 = (bx - chunk * nTx) * BN;
    const int m0 = blockIdx.y * BM;
    const int bz = blockIdx.z;
    const int kbase = chunk * klen;

    const __bf16* A  = Aall + (long)bz * sA;
    const __bf16* Bt = Ball + (long)bz * sB;

    __shared__ alignas(16) __bf16 As[2][BM * BK];
    __shared__ alignas(16) __bf16 Bs[2][BN * BK];

    const int tid = threadIdx.x;
    const int wave = tid >> 6, lane = tid & 63;
    const int wm = (wave >> 1) * 64, wn = (wave & 1) * 64;
    const int quad = lane >> 4, l16 = lane & 15;

    const int row0 = tid >> 2, sl0 = tid & 3;
    const int ks0 = (sl0 - (row0 >> 1)) & 3;
    const int row1 = row0 + 64;
    const int ks1 = (sl0 - (row1 >> 1)) & 3;
    const __bf16* gA0 = A  + (long)(m0 + row0) * K + kbase + ks0 * 8;
    const __bf16* gA1 = A  + (long)(m0 + row1) * K + kbase + ks1 * 8;
    const __bf16* gB0 = Bt + (long)(n0 + row0) * ldb + kbase + ks0 * 8;
    const __bf16* gB1 = Bt + (long)(n0 + row1) * ldb + kbase + ks1 * 8;

    f32x4 acc[4][4];
    #pragma unroll
    for (int i = 0; i < 4; i++)
        #pragma unroll
        for (int j = 0; j < 4; j++) { f32x4 z = {0.f, 0.f, 0.f, 0.f}; acc[i][j] = z; }

    auto stageg = [&](int buf) {          // 4 DMA ops, advances global ptrs
        async_cp16(gA0, As[buf] + wave * 512);
        async_cp16(gA1, As[buf] + 2048 + wave * 512);
        async_cp16(gB0, Bs[buf] + wave * 512);
        async_cp16(gB1, Bs[buf] + 2048 + wave * 512);
        gA0 += BK; gA1 += BK; gB0 += BK; gB1 += BK;
    };

    stageg(0);
    int cur = 0;
    for (int kk = 0; kk < klen; kk += BK) {
        __syncthreads();                  // stage(kk) complete; reads of cur^1 done
        if (kk + BK < klen) stageg(cur ^ 1);

        bf16x8 af[4], bg[4];
        #pragma unroll
        for (int i = 0; i < 4; i++) {
            af[i] = *(const bf16x8*)(As[cur] + swz(wm + i * 16 + l16, quad));
            bg[i] = *(const bf16x8*)(Bs[cur] + swz(wn + i * 16 + l16, quad));
        }
        #pragma unroll
        for (int i = 0; i < 4; i++)
            #pragma unroll
            for (int j = 0; j < 4; j++)
                acc[i][j] = __builtin_amdgcn_mfma_f32_16x16x32_bf16(af[i], bg[j], acc[i][j], 0, 0, 0);
        cur ^= 1;
    }

    char* cb = (char*)C0 + (EPI == 3 ? (long)chunk * pstrideB : 0);
    #pragma unroll
    for (int j = 0; j < 4; j++) {
        const int col = n0 + wn + j * 16 + l16;
        const float bv = (EPI == 2) ? bias[col] : 0.f;
        #pragma unroll
        for (int i = 0; i < 4; i++) {
            #pragma unroll
            for (int r = 0; r < 4; r++) {
                const int row = m0 + wm + i * 16 + quad * 4 + r;  // C/D: row=(lane>>4)*4+reg
                float c = acc[i][j][r];
                if (EPI == 2) { c += bv; c = c > 0.f ? c : 0.2f * c; }
                if (EPI == 1 || EPI == 3)
                    ((__bf16*)cb)[(long)bz * sC + (long)row * N + col] = (__bf16)c;
                else if (EPI == 2)
                    ((__bf16*)cb)[(long)row * N + col] = (__bf16)c;
                else {  // EPI == 4
                    const int seg = col >> 8;
                    __bf16* dst = seg == 0 ? (__bf16*)C0 : (seg == 1 ? (__bf16*)C1 : (__bf16*)C2);
                    dst[(long)row * 256 + (col & 255)] = (__bf16)c;
                }
            }
        }
    }
}

// ---------------------------------------------------------------------------
// Fused attention (verified R8 core): 64 q-rows/block, KVBLK=32, LDS 69KB ->
// 2 blocks/CU at 4 waves/SIMD (regs ~92 <= 128 cap; R4/R7: exceeding 128
// spills catastrophically).
// QK^T: wave-pair (wave>>1) owns 16 q, wave&1 splits 16-key halves; P ->
// XOR-swizzled LDS. Accumulator chain split in two (ILP).
// PV register-blocked: waves re-partition (wave>>2 = 32q set, wave&3 = 64e
// quarter); each V fragment feeds 2 MFMAs.
// CAUSAL LOAD-BALANCE (R9): NS=4 chunks -> max block = 32 tiles (was 64,
// which made causal as slow as cross despite half the FLOPs). Blocks with
// ntile==0 (mt<NS/2) write zero partials/side - epilogue handles naturally.
// ---------------------------------------------------------------------------
template<int CAUSAL>
__launch_bounds__(512, 4)
__global__ void fattn(const __bf16* __restrict__ Qall, const __bf16* __restrict__ Kall,
                      const __bf16* __restrict__ Vt,
                      __bf16* __restrict__ pbuf, float* __restrict__ side,
                      int NS, long pstrideE, float scale)
{
    constexpr int S = 4096, D = 256, R = 16384;
    const int mt = CAUSAL ? (int)(gridDim.x - 1 - blockIdx.x) : (int)blockIdx.x;
    const int chunk = blockIdx.y;
    const int bz = blockIdx.z;
    const int m0 = mt * 64;

    const int T = CAUSAL ? ((m0 + 64) >> 5) : (S >> 5);   // total 32-key tiles
    const int t0 = chunk * T / NS;
    const int t1 = (chunk + 1) * T / NS;
    const int kbase = t0 << 5;
    const int ntile = t1 - t0;

    const __bf16* Q  = Qall + ((long)bz * S + m0) * D;
    const __bf16* Kp = Kall + (long)bz * S * D;
    const long vcol0 = (long)bz * S;

    __shared__ alignas(16) __bf16 Ks[2][8192];   // [buf][kd 0..7][32 key][32 d] swizzled
    __shared__ alignas(16) __bf16 Vs[2][8192];   // [buf][256 e][32 k] swizzled
    __shared__ alignas(16) __bf16 Ps[64 * 32];   // [q][4 slots x 8] slot ^= (q>>1)&3
    __shared__ float sred[8][16];

    const int tid = threadIdx.x;
    const int wave = tid >> 6, lane = tid & 63;
    const int quad = lane >> 4, l16 = lane & 15;
    const int wq16 = (wave >> 1) * 16;
    const int wk16 = (wave & 1) * 16;   // key half in QK^T
    const int qh = wave >> 2;           // PV: 32q set
    const int eq = wave & 3;            // PV: 64e quarter

    // ---- persistent Q fragments: 16 rows x 256 d per wave-pair (32 VGPR) ----
    bf16x8 qf[8];
    #pragma unroll
    for (int kd = 0; kd < 8; kd++)
        qf[kd] = *(const bf16x8*)(Q + (long)(wq16 + l16) * D + kd * 32 + quad * 8);

    // ---- staging geometry (identical to verified R6/R8) ----
    const int srowK = (tid >> 2) & 31;
    const int srowV = tid >> 2;                        // 0..127
    const int ks8 = (((tid & 3) - (tid >> 3)) & 3) << 3;
    const int wbase = (tid & ~63) * 8;                 // wave*512 shorts

    f32x4 acc[2][4];                     // [q-subtile][e-16-col]: 32 regs
    #pragma unroll
    for (int i = 0; i < 2; i++)
        #pragma unroll
        for (int j = 0; j < 4; j++) { f32x4 z = {0.f, 0.f, 0.f, 0.f}; acc[i][j] = z; }
    float se[4] = {0.f, 0.f, 0.f, 0.f};

    auto stage = [&](int buf, int kb) {               // exactly 4 vmem ops
        const __bf16* gK = Kp + (long)(kb + srowK) * D + ks8 + ((tid >> 7) << 5);
        async_cp16(gK,       Ks[buf] + wbase);
        async_cp16(gK + 128, Ks[buf] + 4096 + wbase);
        const __bf16* gV = Vt + vcol0 + kb + ks8 + (long)srowV * R;
        async_cp16(gV,                 Vs[buf] + wbase);
        async_cp16(gV + (long)128 * R, Vs[buf] + 4096 + wbase);
    };

    if (ntile > 0) stage(0, kbase);

    for (int t = 0; t < ntile; ++t) {
        const int cur = t & 1;
        const int kb = kbase + (t << 5);
        __syncthreads();                   // buf[cur] staged; prev P/V reads done
        if (t + 1 < ntile) stage(cur ^ 1, kb + 32);

        const __bf16* Kb_ = Ks[cur];
        const __bf16* Vb_ = Vs[cur];

        // --- QK^T: 16 q x 16 keys (wave's half), d=256; 2 split chains ---
        f32x4 sa = {0.f, 0.f, 0.f, 0.f}, sb = {0.f, 0.f, 0.f, 0.f};
        #pragma unroll
        for (int kd = 0; kd < 4; kd++) {
            bf16x8 b0 = *(const bf16x8*)(Kb_ + kd * 1024 + swz(wk16 + l16, quad));
            bf16x8 b1 = *(const bf16x8*)(Kb_ + (kd + 4) * 1024 + swz(wk16 + l16, quad));
            sa = __builtin_amdgcn_mfma_f32_16x16x32_bf16(qf[kd], b0, sa, 0, 0, 0);
            sb = __builtin_amdgcn_mfma_f32_16x16x32_bf16(qf[kd + 4], b1, sb, 0, 0, 0);
        }

        // --- exp + mask + row-sum + P -> LDS (swizzled, R6 layout) ---
        const bool diag = CAUSAL && (kb >= m0);
        const int kloc = wk16 + l16;
        #pragma unroll
        for (int r = 0; r < 4; r++) {
            const int qloc = wq16 + quad * 4 + r;
            float e = __expf((sa[r] + sb[r]) * scale);
            if (diag && kb + kloc > m0 + qloc) e = 0.f;
            se[r] += e;
            Ps[qloc * 32 + (((kloc >> 3) ^ ((qloc >> 1) & 3)) << 3) + (kloc & 7)] = (__bf16)e;
        }
        __syncthreads();                   // P visible

        // --- PV: O[32q x 64e] per wave += P[32q x 32k] * V[32k x 64e] ---
        {
            const int q0 = qh * 32 + l16;
            const int q1 = q0 + 16;        // ((q1>>1)&3) == ((q0>>1)&3)
            const int sx = ((quad ^ ((q0 >> 1) & 3)) << 3);
            bf16x8 pa0 = *(const bf16x8*)(Ps + q0 * 32 + sx);
            bf16x8 pa1 = *(const bf16x8*)(Ps + q1 * 32 + sx);
            #pragma unroll
            for (int j = 0; j < 4; j++) {
                bf16x8 vb = *(const bf16x8*)(Vb_ + swz(eq * 64 + j * 16 + l16, quad));
                acc[0][j] = __builtin_amdgcn_mfma_f32_16x16x32_bf16(pa0, vb, acc[0][j], 0, 0, 0);
                acc[1][j] = __builtin_amdgcn_mfma_f32_16x16x32_bf16(pa1, vb, acc[1][j], 0, 0, 0);
            }
        }
    }

    // ---- row sums: reduce over 16 key-lanes, then across wk partner waves ----
    #pragma unroll
    for (int st = 1; st < 16; st <<= 1)
        #pragma unroll
        for (int r = 0; r < 4; r++) se[r] += __shfl_xor(se[r], st);
    if (l16 == 0)
        #pragma unroll
        for (int r = 0; r < 4; r++)
            sred[wave][quad * 4 + r] = se[r];
    __syncthreads();
    if ((wave & 1) == 0 && l16 == 0) {
        float* sd = side + ((long)bz * 64 + chunk) * 4096 + m0 + wq16;
        #pragma unroll
        for (int r = 0; r < 4; r++) {
            const int idx = quad * 4 + r;
            sd[idx] = sred[wave][idx] + sred[wave + 1][idx];
        }
    }

    // ---- write unnormalized PV partial (zeros when ntile==0) ----
    __bf16* cb = pbuf + (long)chunk * pstrideE + ((long)bz * S + m0) * D;
    #pragma unroll
    for (int j = 0; j < 4; j++) {
        const int col = eq * 64 + j * 16 + l16;
        #pragma unroll
        for (int i = 0; i < 2; i++)
            #pragma unroll
            for (int r = 0; r < 4; r++)
                cb[(long)(qh * 32 + i * 16 + quad * 4 + r) * D + col] = (__bf16)acc[i][j][r];
    }
}

// (sum of NP bf16 partials) [/ rowsum from side slots 0..lim) ] + residual
// (+ col-bias) -> LayerNorm(D=256).  reduce_inv folded in: each row sums its
// <=4 side slots inline (L1/L2-served, same line per row-group).
template<int NP>
__launch_bounds__(256)
__global__ void ln_res(const __bf16* __restrict__ p, long pstr,
                       const float* __restrict__ resid,
                       const float* __restrict__ side, int lim,
                       const float* __restrict__ bias,
                       const float* __restrict__ gamma, const float* __restrict__ beta,
                       float* __restrict__ outf, __bf16* __restrict__ outb)
{
    const int row  = blockIdx.x * 4 + (threadIdx.x >> 6);
    const int lane = threadIdx.x & 63;
    const long vi = (long)row * 64 + lane;
    float p0 = 0.f, p1 = 0.f, p2 = 0.f, p3 = 0.f;
    #pragma unroll
    for (int i = 0; i < NP; i++) {
        bf16x4 vp = ((const bf16x4*)(p + (long)i * pstr))[vi];
        p0 += (float)vp[0]; p1 += (float)vp[1]; p2 += (float)vp[2]; p3 += (float)vp[3];
    }
    if (side) {
        const float* sp = side + (long)(row >> 12) * 64 * 4096 + (row & 4095);
        float sv = 0.f;
        for (int t = 0; t < lim; t++) sv += sp[(long)t * 4096];
        const float iv = 1.f / sv;
        p0 *= iv; p1 *= iv; p2 *= iv; p3 *= iv;
    }
    float4 vr = ((const float4*)resid)[vi];
    float x0 = vr.x + p0, x1 = vr.y + p1, x2 = vr.z + p2, x3 = vr.w + p3;
    if (bias) {
        float4 vb = ((const float4*)bias)[lane];
        x0 += vb.x; x1 += vb.y; x2 += vb.z; x3 += vb.w;
    }
    float s = x0 + x1 + x2 + x3;
    #pragma unroll
    for (int off = 32; off; off >>= 1) s += __shfl_xor(s, off);
    const float mu = s * (1.f / 256.f);
    float d0 = x0 - mu, d1 = x1 - mu, d2 = x2 - mu, d3 = x3 - mu;
    float s2 = d0 * d0 + d1 * d1 + d2 * d2 + d3 * d3;
    #pragma unroll
    for (int off = 32; off; off >>= 1) s2 += __shfl_xor(s2, off);
    const float rs = rsqrtf(s2 * (1.f / 256.f) + 1e-3f);
    const float4 g  = ((const float4*)gamma)[lane];
    const float4 be = ((const float4*)beta)[lane];
    float o0 = d0 * rs * g.x + be.x, o1 = d1 * rs * g.y + be.y;
    float o2 = d2 * rs * g.z + be.z, o3 = d3 * rs * g.w + be.w;
    float4 o; o.x = o0; o.y = o1; o.z = o2; o.w = o3;
    ((float4*)outf)[vi] = o;
    if (outb) {
        bf16x4 ob; ob[0] = (__bf16)o0; ob[1] = (__bf16)o1; ob[2] = (__bf16)o2; ob[3] = (__bf16)o3;
        ((bf16x4*)outb)[vi] = ob;
    }
}

__device__ __forceinline__ void tp(const float* __restrict__ src, __bf16* __restrict__ dst,
                                   int rows, int cols, int rowsP, int i)
{
    const int c = i / rowsP, r = i - c * rowsP;
    const float v = (r < rows && c < cols) ? src[r * cols + c] : 0.f;
    dst[i] = (__bf16)v;
}

// one kernel for all prep: fp32->bf16 converts + weight transposes + bias pad
__global__ void prep_all(const float4* __restrict__ inA, const float4* __restrict__ inC,
                         bf16x4* __restrict__ outA, bf16x4* __restrict__ outC,
                         const float* __restrict__ sWq, const float* __restrict__ sWk,
                         const float* __restrict__ sWv,
                         const float* __restrict__ cWq, const float* __restrict__ cWk,
                         const float* __restrict__ cWv,
                         const float* __restrict__ W1, const float* __restrict__ W2,
                         __bf16* __restrict__ wqk_s, __bf16* __restrict__ wv_s,
                         __bf16* __restrict__ wq_c, __bf16* __restrict__ wk_c,
                         __bf16* __restrict__ wv_c,
                         __bf16* __restrict__ W1t, __bf16* __restrict__ W2t,
                         const float* __restrict__ b1, float* __restrict__ b1p)
{
    const int bx = blockIdx.x, tid = threadIdx.x;
    if (bx < 8192) {
        const bool a = bx < 4096;
        const long j = (long)(a ? bx : bx - 4096) * 256 + tid;
        float4 v = (a ? inA : inC)[j];
        bf16x4 o; o[0] = (__bf16)v.x; o[1] = (__bf16)v.y; o[2] = (__bf16)v.z; o[3] = (__bf16)v.w;
        (a ? outA : outC)[j] = o;
    }
    else if (bx < 8448)  tp(sWq, wqk_s,          256, 256, 256, (bx - 8192)  * 256 + tid);
    else if (bx < 8704)  tp(sWk, wqk_s + 65536,  256, 256, 256, (bx - 8448)  * 256 + tid);
    else if (bx < 8960)  tp(sWv, wv_s,           256, 256, 256, (bx - 8704)  * 256 + tid);
    else if (bx < 9216)  tp(cWq, wq_c,           256, 256, 256, (bx - 8960)  * 256 + tid);
    else if (bx < 9472)  tp(cWk, wk_c,           256, 256, 256, (bx - 9216)  * 256 + tid);
    else if (bx < 9728)  tp(cWv, wv_c,           256, 256, 256, (bx - 9472)  * 256 + tid);
    else if (bx < 10240) tp(W1,  W1t,            256, 400, 256, (bx - 9728)  * 256 + tid);
    else if (bx < 10752) tp(W2,  W2t,            400, 256, 512, (bx - 10240) * 256 + tid);
    else { const int i = (bx - 10752) * 256 + tid; if (i < 512) b1p[i] = (i < 400) ? b1[i] : 0.f; }
}

extern "C" void kernel_launch(void* const* d_in, const int* in_sizes, int n_in,
                              void* d_out, int out_size, void* d_ws, size_t ws_size,
                              hipStream_t stream)
{
    constexpr int B = 4, S = 4096, D = 256, H = 400, Hp = 512;
    constexpr int R = B * S;
    constexpr float SCALE = 1.f / 64.f;   // 1/sqrt(4096)
    constexpr int NSc = 4;                // causal chunks (64x4x4 = 1024 blocks, max 32 tiles)
    constexpr int NSx = 2;                // cross chunks   (64x2x4 = 512 blocks, 64 tiles)
    constexpr int NSf = 2;                // FFN K-split

    const float* inputs = (const float*)d_in[0];
    const float* ctx    = (const float*)d_in[1];
    const float* sa_Wk  = (const float*)d_in[2];
    const float* sa_Wv  = (const float*)d_in[3];
    const float* sa_Wq  = (const float*)d_in[4];
    const float* ca_Wk  = (const float*)d_in[5];
    const float* ca_Wv  = (const float*)d_in[6];
    const float* ca_Wq  = (const float*)d_in[7];
    const float* W1     = (const float*)d_in[8];
    const float* b1     = (const float*)d_in[9];
    const float* W2     = (const float*)d_in[10];
    const float* b2     = (const float*)d_in[11];
    const float* gamma  = (const float*)d_in[12];
    const float* beta   = (const float*)d_in[13];
    float* out = (float*)d_out;

    char* ws = (char*)d_ws;
    size_t off = 0;
    auto alloc = [&](size_t bytes) -> char* {
        char* p = ws + off; off += (bytes + 255) & ~size_t(255); return p;
    };
    // NOTE: adjacency is load-bearing for z-batched GEMMs:
    //   bfA|bfC, Qb|Kb, wv_s|wv_c, wq_c|wk_c  (all sizes multiple of 256B)
    __bf16* bfA  = (__bf16*)alloc((size_t)R * D * 2);     // bf16(inputs) -> xbf
    __bf16* bfC  = (__bf16*)alloc((size_t)R * D * 2);     // bf16(context) -> ybf
    __bf16* Qb   = (__bf16*)alloc((size_t)R * D * 2);
    __bf16* Kb   = (__bf16*)alloc((size_t)R * D * 2);
    __bf16* Vt   = (__bf16*)alloc((size_t)2 * D * R * 2); // V^T self | V^T cross
    __bf16* h    = (__bf16*)alloc((size_t)R * Hp * 2);    // FFN hidden
    float*  x    = (float*)alloc((size_t)R * D * 4);
    float*  y    = (float*)alloc((size_t)R * D * 4);
    float*  side = (float*)alloc((size_t)B * 64 * S * 4); // row-sums per chunk slot
    __bf16* wqk_s = (__bf16*)alloc((size_t)2 * D * D * 2); // [Wq^T | Wk^T] (self)
    __bf16* wv_s  = (__bf16*)alloc((size_t)D * D * 2);
    __bf16* wv_c  = (__bf16*)alloc((size_t)D * D * 2);
    __bf16* wq_c  = (__bf16*)alloc((size_t)D * D * 2);
    __bf16* wk_c  = (__bf16*)alloc((size_t)D * D * 2);
    __bf16* W1t  = (__bf16*)alloc((size_t)Hp * D * 2);
    __bf16* W2t  = (__bf16*)alloc((size_t)D * Hp * 2);
    float*  b1p  = (float*)alloc((size_t)Hp * 4);

    const size_t PBb = (size_t)R * D * 2;                 // one bf16 partial (8MB)
    __bf16* pbuf = (__bf16*)alloc((size_t)4 * PBb);       // up to 4 partials
    if (off > ws_size) return;                            // workspace too small
    const long PBe = (long)R * D;                         // partial stride (elements)

    __bf16* xbf = bfA;
    __bf16* ybf = bfC;

    const dim3 blk(256);
    const dim3 blk512(512);

    auto launch_ln = [&](int np, const float* res, const float* sd, int lim,
                         const float* bias, float* of, __bf16* ob) {
        if (np == 4)      ln_res<4><<<R / 4, blk, 0, stream>>>(pbuf, PBe, res, sd, lim, bias, gamma, beta, of, ob);
        else if (np == 2) ln_res<2><<<R / 4, blk, 0, stream>>>(pbuf, PBe, res, sd, lim, bias, gamma, beta, of, ob);
        else              ln_res<1><<<R / 4, blk, 0, stream>>>(pbuf, PBe, res, sd, lim, bias, gamma, beta, of, ob);
    };

    // --- prep (single consolidated dispatch) ---
    prep_all<<<10754, blk, 0, stream>>>((const float4*)inputs, (const float4*)ctx,
        (bf16x4*)bfA, (bf16x4*)bfC, sa_Wq, sa_Wk, sa_Wv, ca_Wq, ca_Wk, ca_Wv, W1, W2,
        wqk_s, wv_s, wq_c, wk_c, wv_c, W1t, W2t, b1, b1p);

    // --- self QK projection ([Q|K] = bfA x [Wq^T|Wk^T]) ---
    gemm_nt<4><<<dim3(4, 128, 1), blk, 0, stream>>>(bfA, wqk_s, nullptr,
        Qb, Kb, nullptr, 2 * D, D, D, 0, 0, 0, 4, D, 0);
    // --- BOTH V^T upfront (z=0: self from bfA, z=1: cross from bfC) ---
    gemm_nt<1><<<dim3(128, 2, 2), blk, 0, stream>>>(wv_s, bfA, nullptr,
        Vt, nullptr, nullptr, R, D, D, (long)D * D, (long)R * D, (long)D * R, 128, D, 0);

    // --- self-attention (causal, fused, load-balanced) ---
    fattn<1><<<dim3(64, NSc, B), blk512, 0, stream>>>(Qb, Kb, Vt, pbuf, side, NSc, PBe, SCALE);
    launch_ln(NSc, inputs, side, NSc, nullptr, x, xbf);

    // --- cross Q,K projections in one dispatch (z=0: Q=xbf*Wq, z=1: K=bfC*Wk) ---
    gemm_nt<1><<<dim3(2, 128, 2), blk, 0, stream>>>(xbf, wq_c, nullptr,
        Qb, nullptr, nullptr, D, D, D, (long)R * D, (long)D * D, (long)R * D, 2, D, 0);

    // --- cross-attention (full, fused) ---
    fattn<0><<<dim3(64, NSx, B), blk512, 0, stream>>>(Qb, Kb, Vt + (size_t)D * R,
        pbuf, side, NSx, PBe, SCALE);
    launch_ln(NSx, x, side, NSx, nullptr, y, ybf);

    // --- FFN ---
    gemm_nt<2><<<dim3(4, 128, 1), blk, 0, stream>>>(ybf, W1t, b1p,
        h, nullptr, nullptr, Hp, D, D, 0, 0, 0, 4, D, 0);
    gemm_nt<3><<<dim3(2 * NSf, 128, 1), blk, 0, stream>>>(h, W2t, nullptr,
        pbuf, nullptr, nullptr, D, Hp, Hp, 0, 0, 0, 2, Hp / NSf, (long)PBb);
    launch_ln(NSf, y, nullptr, 0, b2, out, nullptr);   // b2 folded into pre-LN sum
}

// Round 10
// 384.121 us; speedup vs baseline: 1.0304x; 1.0304x over previous
//
#include <hip/hip_runtime.h>

typedef __bf16  bf16x4 __attribute__((ext_vector_type(4)));
typedef __bf16  bf16x8 __attribute__((ext_vector_type(8)));
typedef float   f32x4  __attribute__((ext_vector_type(4)));
typedef unsigned int u32;

constexpr int BM = 128, BN = 128, BK = 32;

// async global->LDS, 16B per lane. LDS dest is wave-uniform base + lane*16.
__device__ __forceinline__ void async_cp16(const __bf16* g, __bf16* lds) {
    __builtin_amdgcn_global_load_lds(
        (const __attribute__((address_space(1))) u32*)g,
        (__attribute__((address_space(3))) u32*)lds, 16, 0, 0);
}

// swizzled LDS offset (in shorts) of (row, 16B-slot q) for 32-wide rows
__device__ __forceinline__ int swz(int row, int q) {
    return row * BK + (((q + (row >> 1)) & 3) << 3);
}

// counted-vmcnt raw-barrier helpers (R1-proven pattern)
#define ASM_LGKM0 asm volatile("s_waitcnt lgkmcnt(0)" ::: "memory")
#define ASM_VM2   asm volatile("s_waitcnt vmcnt(2)" ::: "memory")
#define ASM_VM0   asm volatile("s_waitcnt vmcnt(0)" ::: "memory")
#define SBAR()    do { __builtin_amdgcn_s_barrier(); asm volatile("" ::: "memory"); } while (0)

// ---------------------------------------------------------------------------
// NT GEMM (128x128xBK32), LDS double-buffered: stage(t+1) issued before the
// compute of tile t, ONE barrier per K-step -> DMA latency hides under MFMA.
// EPI: 1 = bf16 store, 2 = +bias,leakyRelu -> bf16,
//      3 = bf16 partial at C0 + chunk*pstrideB,
//      4 = bf16 split across C0/C1/C2 by col/256
// blockIdx.z batches independent (A,B,C) triples via sA/sB/sC strides.
// ---------------------------------------------------------------------------
template<int EPI>
__launch_bounds__(256)
__global__ void gemm_nt(const __bf16* __restrict__ Aall, const __bf16* __restrict__ Ball,
                        const float* __restrict__ bias,
                        void* __restrict__ C0, void* __restrict__ C1, void* __restrict__ C2,
                        int N, int K, long ldb, long sA, long sB, long sC,
                        int nTx, int klen, long pstrideB)
{
    const int bx = blockIdx.x;
    const int chunk = bx / nTx;
    const int n0 = (bx - chunk * nTx) * BN;
    const int m0 = blockIdx.y * BM;
    const int bz = blockIdx.z;
    const int kbase = chunk * klen;

    const __bf16* A  = Aall + (long)bz * sA;
    const __bf16* Bt = Ball + (long)bz * sB;

    __shared__ alignas(16) __bf16 As[2][BM * BK];
    __shared__ alignas(16) __bf16 Bs[2][BN * BK];

    const int tid = threadIdx.x;
    const int wave = tid >> 6, lane = tid & 63;
    const int wm = (wave >> 1) * 64, wn = (wave & 1) * 64;
    const int quad = lane >> 4, l16 = lane & 15;

    const int row0 = tid >> 2, sl0 = tid & 3;
    const int ks0 = (sl0 - (row0 >> 1)) & 3;
    const int row1 = row0 + 64;
    const int ks1 = (sl0 - (row1 >> 1)) & 3;
    const __bf16* gA0 = A  + (long)(m0 + row0) * K + kbase + ks0 * 8;
    const __bf16* gA1 = A  + (long)(m0 + row1) * K + kbase + ks1 * 8;
    const __bf16* gB0 = Bt + (long)(n0 + row0) * ldb + kbase + ks0 * 8;
    const __bf16* gB1 = Bt + (long)(n0 + row1) * ldb + kbase + ks1 * 8;

    f32x4 acc[4][4];
    #pragma unroll
    for (int i = 0; i < 4; i++)
        #pragma unroll
        for (int j = 0; j < 4; j++) { f32x4 z = {0.f, 0.f, 0.f, 0.f}; acc[i][j] = z; }

    auto stageg = [&](int buf) {          // 4 DMA ops, advances global ptrs
        async_cp16(gA0, As[buf] + wave * 512);
        async_cp16(gA1, As[buf] + 2048 + wave * 512);
        async_cp16(gB0, Bs[buf] + wave * 512);
        async_cp16(gB1, Bs[buf] + 2048 + wave * 512);
        gA0 += BK; gA1 += BK; gB0 += BK; gB1 += BK;
    };

    stageg(0);
    int cur = 0;
    for (int kk = 0; kk < klen; kk += BK) {
        __syncthreads();                  // stage(kk) complete; reads of cur^1 done
        if (kk + BK < klen) stageg(cur ^ 1);

        bf16x8 af[4], bg[4];
        #pragma unroll
        for (int i = 0; i < 4; i++) {
            af[i] = *(const bf16x8*)(As[cur] + swz(wm + i * 16 + l16, quad));
            bg[i] = *(const bf16x8*)(Bs[cur] + swz(wn + i * 16 + l16, quad));
        }
        #pragma unroll
        for (int i = 0; i < 4; i++)
            #pragma unroll
            for (int j = 0; j < 4; j++)
                acc[i][j] = __builtin_amdgcn_mfma_f32_16x16x32_bf16(af[i], bg[j], acc[i][j], 0, 0, 0);
        cur ^= 1;
    }

    char* cb = (char*)C0 + (EPI == 3 ? (long)chunk * pstrideB : 0);
    #pragma unroll
    for (int j = 0; j < 4; j++) {
        const int col = n0 + wn + j * 16 + l16;
        const float bv = (EPI == 2) ? bias[col] : 0.f;
        #pragma unroll
        for (int i = 0; i < 4; i++) {
            #pragma unroll
            for (int r = 0; r < 4; r++) {
                const int row = m0 + wm + i * 16 + quad * 4 + r;  // C/D: row=(lane>>4)*4+reg
                float c = acc[i][j][r];
                if (EPI == 2) { c += bv; c = c > 0.f ? c : 0.2f * c; }
                if (EPI == 1 || EPI == 3)
                    ((__bf16*)cb)[(long)bz * sC + (long)row * N + col] = (__bf16)c;
                else if (EPI == 2)
                    ((__bf16*)cb)[(long)row * N + col] = (__bf16)c;
                else {  // EPI == 4
                    const int seg = col >> 8;
                    __bf16* dst = seg == 0 ? (__bf16*)C0 : (seg == 1 ? (__bf16*)C1 : (__bf16*)C2);
                    dst[(long)row * 256 + (col & 255)] = (__bf16)c;
                }
            }
        }
    }
}

// ---------------------------------------------------------------------------
// Fused attention, 2-phase pipelined (R10): 64 q-rows/block, KVBLK=32,
// LDS = Ks[2]32K + Vs[2]32K + Ps[2]8K = 72.5KB -> 2 blocks/CU, 4 waves/SIMD.
// Need-time analysis: K(t) needed phase1(t); V(t) needed phase1(t+1);
// Ps(t) needed phase1(t+1). So:
//   phase1(t): QK(t) MFMAs INTERLEAVED with PV(t-1) MFMAs (two independent
//              chains for the MFMA pipe) + issue K(t+1) DMA.
//   phase2(t): issue V(t+1) DMA + exp(t) + Ps[t&1] write.
// Barrier A = lgkm0 + vmcnt(2) (leaves newest V in flight: guarantees exactly
// {K(t), V(t-1)} complete). Barrier B = lgkm0 only (no DMA drain).
// V prefetch distance = one full tile (was ~300cy -> the per-tile stall).
// Buffer hazards audited: K(t+1)->Ks[cur^1] unread during phase1;
// V(t+1)->Vs[cur^1] issued after barrier B retires PV(t-1) reads of it;
// Ps[cur] write disjoint from Ps[cur^1] read. Regs ~90 (128-cap safe).
// ---------------------------------------------------------------------------
template<int CAUSAL>
__launch_bounds__(512, 4)
__global__ void fattn(const __bf16* __restrict__ Qall, const __bf16* __restrict__ Kall,
                      const __bf16* __restrict__ Vt,
                      __bf16* __restrict__ pbuf, float* __restrict__ side,
                      int NS, long pstrideE, float scale)
{
    constexpr int S = 4096, D = 256, R = 16384;
    const int mt = CAUSAL ? (int)(gridDim.x - 1 - blockIdx.x) : (int)blockIdx.x;
    const int chunk = blockIdx.y;
    const int bz = blockIdx.z;
    const int m0 = mt * 64;

    const int T = CAUSAL ? ((m0 + 64) >> 5) : (S >> 5);   // total 32-key tiles
    const int t0 = chunk * T / NS;
    const int t1 = (chunk + 1) * T / NS;
    const int kbase = t0 << 5;
    const int ntile = t1 - t0;

    const __bf16* Q  = Qall + ((long)bz * S + m0) * D;
    const __bf16* Kp = Kall + (long)bz * S * D;
    const long vcol0 = (long)bz * S;

    __shared__ alignas(16) __bf16 Ks[2][8192];   // [buf][kd 0..7][32 key][32 d] swizzled
    __shared__ alignas(16) __bf16 Vs[2][8192];   // [buf][256 e][32 k] swizzled
    __shared__ alignas(16) __bf16 Ps[2][2048];   // [buf][64 q][4 slots x 8] slot ^= (q>>1)&3
    __shared__ float sred[8][16];

    const int tid = threadIdx.x;
    const int wave = tid >> 6, lane = tid & 63;
    const int quad = lane >> 4, l16 = lane & 15;
    const int wq16 = (wave >> 1) * 16;
    const int wk16 = (wave & 1) * 16;   // key half in QK^T
    const int qh = wave >> 2;           // PV: 32q set
    const int eq = wave & 3;            // PV: 64e quarter

    // ---- persistent Q fragments: 16 rows x 256 d per wave-pair (32 VGPR) ----
    bf16x8 qf[8];
    #pragma unroll
    for (int kd = 0; kd < 8; kd++)
        qf[kd] = *(const bf16x8*)(Q + (long)(wq16 + l16) * D + kd * 32 + quad * 8);

    // ---- staging geometry (identical to verified R6/R8) ----
    const int srowK = (tid >> 2) & 31;
    const int srowV = tid >> 2;                        // 0..127
    const int ks8 = (((tid & 3) - (tid >> 3)) & 3) << 3;
    const int wbase = (tid & ~63) * 8;                 // wave*512 shorts

    f32x4 acc[2][4];                     // [q-subtile][e-16-col]: 32 regs
    #pragma unroll
    for (int i = 0; i < 2; i++)
        #pragma unroll
        for (int j = 0; j < 4; j++) { f32x4 z = {0.f, 0.f, 0.f, 0.f}; acc[i][j] = z; }
    float se[4] = {0.f, 0.f, 0.f, 0.f};

    auto stageK = [&](int buf, int kb) {              // 2 DMA ops
        const __bf16* gK = Kp + (long)(kb + srowK) * D + ks8 + ((tid >> 7) << 5);
        async_cp16(gK,       Ks[buf] + wbase);
        async_cp16(gK + 128, Ks[buf] + 4096 + wbase);
    };
    auto stageV = [&](int buf, int kb) {              // 2 DMA ops
        const __bf16* gV = Vt + vcol0 + kb + ks8 + (long)srowV * R;
        async_cp16(gV,                 Vs[buf] + wbase);
        async_cp16(gV + (long)128 * R, Vs[buf] + 4096 + wbase);
    };

    // PV helper operands (constant per thread)
    const int q0 = qh * 32 + l16;
    const int q1 = q0 + 16;              // ((q1>>1)&3) == ((q0>>1)&3)
    const int sx = ((quad ^ ((q0 >> 1) & 3)) << 3);

    if (ntile > 0) { stageK(0, kbase); stageV(0, kbase); }

    for (int t = 0; t < ntile; ++t) {
        const int cur = t & 1;
        const int kb = kbase + (t << 5);
        ASM_LGKM0; ASM_VM2; SBAR();        // A: K(t) + V(t-1) complete; Ps(t-1) visible

        // ---- phase 1: QK(t) || PV(t-1), + issue K(t+1) ----
        const __bf16* Kb_ = Ks[cur];
        f32x4 sa = {0.f, 0.f, 0.f, 0.f}, sb = {0.f, 0.f, 0.f, 0.f};
        #pragma unroll
        for (int kd = 0; kd < 4; kd++) {
            bf16x8 b0 = *(const bf16x8*)(Kb_ + kd * 1024 + swz(wk16 + l16, quad));
            bf16x8 b1 = *(const bf16x8*)(Kb_ + (kd + 4) * 1024 + swz(wk16 + l16, quad));
            sa = __builtin_amdgcn_mfma_f32_16x16x32_bf16(qf[kd], b0, sa, 0, 0, 0);
            sb = __builtin_amdgcn_mfma_f32_16x16x32_bf16(qf[kd + 4], b1, sb, 0, 0, 0);
        }
        if (t > 0) {
            const __bf16* Vb_ = Vs[cur ^ 1];
            const __bf16* Pp = Ps[cur ^ 1];
            bf16x8 pa0 = *(const bf16x8*)(Pp + q0 * 32 + sx);
            bf16x8 pa1 = *(const bf16x8*)(Pp + q1 * 32 + sx);
            #pragma unroll
            for (int j = 0; j < 4; j++) {
                bf16x8 vb = *(const bf16x8*)(Vb_ + swz(eq * 64 + j * 16 + l16, quad));
                acc[0][j] = __builtin_amdgcn_mfma_f32_16x16x32_bf16(pa0, vb, acc[0][j], 0, 0, 0);
                acc[1][j] = __builtin_amdgcn_mfma_f32_16x16x32_bf16(pa1, vb, acc[1][j], 0, 0, 0);
            }
        }
        if (t + 1 < ntile) stageK(cur ^ 1, kb + 32);
        ASM_LGKM0; SBAR();                 // B: phase-1 LDS reads retired (no DMA drain)

        // ---- phase 2: issue V(t+1), exp(t), Ps[cur] write ----
        if (t + 1 < ntile) stageV(cur ^ 1, kb + 32);
        const bool diag = CAUSAL && (kb >= m0);
        const int kloc = wk16 + l16;
        __bf16* Pw = Ps[cur];
        #pragma unroll
        for (int r = 0; r < 4; r++) {
            const int qloc = wq16 + quad * 4 + r;
            float e = __expf((sa[r] + sb[r]) * scale);
            if (diag && kb + kloc > m0 + qloc) e = 0.f;
            se[r] += e;
            Pw[qloc * 32 + (((kloc >> 3) ^ ((qloc >> 1) & 3)) << 3) + (kloc & 7)] = (__bf16)e;
        }
    }

    // ---- drain: final PV for tile ntile-1 ----
    if (ntile > 0) {
        ASM_LGKM0; ASM_VM0; SBAR();
        const int lb = (ntile - 1) & 1;
        const __bf16* Vb_ = Vs[lb];
        const __bf16* Pp = Ps[lb];
        bf16x8 pa0 = *(const bf16x8*)(Pp + q0 * 32 + sx);
        bf16x8 pa1 = *(const bf16x8*)(Pp + q1 * 32 + sx);
        #pragma unroll
        for (int j = 0; j < 4; j++) {
            bf16x8 vb = *(const bf16x8*)(Vb_ + swz(eq * 64 + j * 16 + l16, quad));
            acc[0][j] = __builtin_amdgcn_mfma_f32_16x16x32_bf16(pa0, vb, acc[0][j], 0, 0, 0);
            acc[1][j] = __builtin_amdgcn_mfma_f32_16x16x32_bf16(pa1, vb, acc[1][j], 0, 0, 0);
        }
    }

    // ---- row sums: reduce over 16 key-lanes, then across wk partner waves ----
    #pragma unroll
    for (int st = 1; st < 16; st <<= 1)
        #pragma unroll
        for (int r = 0; r < 4; r++) se[r] += __shfl_xor(se[r], st);
    if (l16 == 0)
        #pragma unroll
        for (int r = 0; r < 4; r++)
            sred[wave][quad * 4 + r] = se[r];
    __syncthreads();
    if ((wave & 1) == 0 && l16 == 0) {
        float* sd = side + ((long)bz * 64 + chunk) * 4096 + m0 + wq16;
        #pragma unroll
        for (int r = 0; r < 4; r++) {
            const int idx = quad * 4 + r;
            sd[idx] = sred[wave][idx] + sred[wave + 1][idx];
        }
    }

    // ---- write unnormalized PV partial (zeros when ntile==0) ----
    __bf16* cb = pbuf + (long)chunk * pstrideE + ((long)bz * S + m0) * D;
    #pragma unroll
    for (int j = 0; j < 4; j++) {
        const int col = eq * 64 + j * 16 + l16;
        #pragma unroll
        for (int i = 0; i < 2; i++)
            #pragma unroll
            for (int r = 0; r < 4; r++)
                cb[(long)(qh * 32 + i * 16 + quad * 4 + r) * D + col] = (__bf16)acc[i][j][r];
    }
}

// (sum of NP bf16 partials) [/ rowsum from side slots 0..lim) ] + residual
// (+ col-bias) -> LayerNorm(D=256).  reduce_inv folded in: each row sums its
// <=4 side slots inline (L1/L2-served, same line per row-group).
template<int NP>
__launch_bounds__(256)
__global__ void ln_res(const __bf16* __restrict__ p, long pstr,
                       const float* __restrict__ resid,
                       const float* __restrict__ side, int lim,
                       const float* __restrict__ bias,
                       const float* __restrict__ gamma, const float* __restrict__ beta,
                       float* __restrict__ outf, __bf16* __restrict__ outb)
{
    const int row  = blockIdx.x * 4 + (threadIdx.x >> 6);
    const int lane = threadIdx.x & 63;
    const long vi = (long)row * 64 + lane;
    float p0 = 0.f, p1 = 0.f, p2 = 0.f, p3 = 0.f;
    #pragma unroll
    for (int i = 0; i < NP; i++) {
        bf16x4 vp = ((const bf16x4*)(p + (long)i * pstr))[vi];
        p0 += (float)vp[0]; p1 += (float)vp[1]; p2 += (float)vp[2]; p3 += (float)vp[3];
    }
    if (side) {
        const float* sp = side + (long)(row >> 12) * 64 * 4096 + (row & 4095);
        float sv = 0.f;
        for (int t = 0; t < lim; t++) sv += sp[(long)t * 4096];
        const float iv = 1.f / sv;
        p0 *= iv; p1 *= iv; p2 *= iv; p3 *= iv;
    }
    float4 vr = ((const float4*)resid)[vi];
    float x0 = vr.x + p0, x1 = vr.y + p1, x2 = vr.z + p2, x3 = vr.w + p3;
    if (bias) {
        float4 vb = ((const float4*)bias)[lane];
        x0 += vb.x; x1 += vb.y; x2 += vb.z; x3 += vb.w;
    }
    float s = x0 + x1 + x2 + x3;
    #pragma unroll
    for (int off = 32; off; off >>= 1) s += __shfl_xor(s, off);
    const float mu = s * (1.f / 256.f);
    float d0 = x0 - mu, d1 = x1 - mu, d2 = x2 - mu, d3 = x3 - mu;
    float s2 = d0 * d0 + d1 * d1 + d2 * d2 + d3 * d3;
    #pragma unroll
    for (int off = 32; off; off >>= 1) s2 += __shfl_xor(s2, off);
    const float rs = rsqrtf(s2 * (1.f / 256.f) + 1e-3f);
    const float4 g  = ((const float4*)gamma)[lane];
    const float4 be = ((const float4*)beta)[lane];
    float o0 = d0 * rs * g.x + be.x, o1 = d1 * rs * g.y + be.y;
    float o2 = d2 * rs * g.z + be.z, o3 = d3 * rs * g.w + be.w;
    float4 o; o.x = o0; o.y = o1; o.z = o2; o.w = o3;
    ((float4*)outf)[vi] = o;
    if (outb) {
        bf16x4 ob; ob[0] = (__bf16)o0; ob[1] = (__bf16)o1; ob[2] = (__bf16)o2; ob[3] = (__bf16)o3;
        ((bf16x4*)outb)[vi] = ob;
    }
}

__device__ __forceinline__ void tp(const float* __restrict__ src, __bf16* __restrict__ dst,
                                   int rows, int cols, int rowsP, int i)
{
    const int c = i / rowsP, r = i - c * rowsP;
    const float v = (r < rows && c < cols) ? src[r * cols + c] : 0.f;
    dst[i] = (__bf16)v;
}

// one kernel for all prep: fp32->bf16 converts + weight transposes + bias pad
__global__ void prep_all(const float4* __restrict__ inA, const float4* __restrict__ inC,
                         bf16x4* __restrict__ outA, bf16x4* __restrict__ outC,
                         const float* __restrict__ sWq, const float* __restrict__ sWk,
                         const float* __restrict__ sWv,
                         const float* __restrict__ cWq, const float* __restrict__ cWk,
                         const float* __restrict__ cWv,
                         const float* __restrict__ W1, const float* __restrict__ W2,
                         __bf16* __restrict__ wqk_s, __bf16* __restrict__ wv_s,
                         __bf16* __restrict__ wq_c, __bf16* __restrict__ wk_c,
                         __bf16* __restrict__ wv_c,
                         __bf16* __restrict__ W1t, __bf16* __restrict__ W2t,
                         const float* __restrict__ b1, float* __restrict__ b1p)
{
    const int bx = blockIdx.x, tid = threadIdx.x;
    if (bx < 8192) {
        const bool a = bx < 4096;
        const long j = (long)(a ? bx : bx - 4096) * 256 + tid;
        float4 v = (a ? inA : inC)[j];
        bf16x4 o; o[0] = (__bf16)v.x; o[1] = (__bf16)v.y; o[2] = (__bf16)v.z; o[3] = (__bf16)v.w;
        (a ? outA : outC)[j] = o;
    }
    else if (bx < 8448)  tp(sWq, wqk_s,          256, 256, 256, (bx - 8192)  * 256 + tid);
    else if (bx < 8704)  tp(sWk, wqk_s + 65536,  256, 256, 256, (bx - 8448)  * 256 + tid);
    else if (bx < 8960)  tp(sWv, wv_s,           256, 256, 256, (bx - 8704)  * 256 + tid);
    else if (bx < 9216)  tp(cWq, wq_c,           256, 256, 256, (bx - 8960)  * 256 + tid);
    else if (bx < 9472)  tp(cWk, wk_c,           256, 256, 256, (bx - 9216)  * 256 + tid);
    else if (bx < 9728)  tp(cWv, wv_c,           256, 256, 256, (bx - 9472)  * 256 + tid);
    else if (bx < 10240) tp(W1,  W1t,            256, 400, 256, (bx - 9728)  * 256 + tid);
    else if (bx < 10752) tp(W2,  W2t,            400, 256, 512, (bx - 10240) * 256 + tid);
    else { const int i = (bx - 10752) * 256 + tid; if (i < 512) b1p[i] = (i < 400) ? b1[i] : 0.f; }
}

extern "C" void kernel_launch(void* const* d_in, const int* in_sizes, int n_in,
                              void* d_out, int out_size, void* d_ws, size_t ws_size,
                              hipStream_t stream)
{
    constexpr int B = 4, S = 4096, D = 256, H = 400, Hp = 512;
    constexpr int R = B * S;
    constexpr float SCALE = 1.f / 64.f;   // 1/sqrt(4096)
    constexpr int NSc = 2;                // causal chunks (64x2x4 = 512 blocks)
    constexpr int NSx = 2;                // cross chunks  (64x2x4 = 512 blocks)
    constexpr int NSf = 2;                // FFN K-split

    const float* inputs = (const float*)d_in[0];
    const float* ctx    = (const float*)d_in[1];
    const float* sa_Wk  = (const float*)d_in[2];
    const float* sa_Wv  = (const float*)d_in[3];
    const float* sa_Wq  = (const float*)d_in[4];
    const float* ca_Wk  = (const float*)d_in[5];
    const float* ca_Wv  = (const float*)d_in[6];
    const float* ca_Wq  = (const float*)d_in[7];
    const float* W1     = (const float*)d_in[8];
    const float* b1     = (const float*)d_in[9];
    const float* W2     = (const float*)d_in[10];
    const float* b2     = (const float*)d_in[11];
    const float* gamma  = (const float*)d_in[12];
    const float* beta   = (const float*)d_in[13];
    float* out = (float*)d_out;

    char* ws = (char*)d_ws;
    size_t off = 0;
    auto alloc = [&](size_t bytes) -> char* {
        char* p = ws + off; off += (bytes + 255) & ~size_t(255); return p;
    };
    // NOTE: adjacency is load-bearing for z-batched GEMMs:
    //   bfA|bfC, Qb|Kb, wv_s|wv_c, wq_c|wk_c  (all sizes multiple of 256B)
    __bf16* bfA  = (__bf16*)alloc((size_t)R * D * 2);     // bf16(inputs) -> xbf
    __bf16* bfC  = (__bf16*)alloc((size_t)R * D * 2);     // bf16(context) -> ybf
    __bf16* Qb   = (__bf16*)alloc((size_t)R * D * 2);
    __bf16* Kb   = (__bf16*)alloc((size_t)R * D * 2);
    __bf16* Vt   = (__bf16*)alloc((size_t)2 * D * R * 2); // V^T self | V^T cross
    __bf16* h    = (__bf16*)alloc((size_t)R * Hp * 2);    // FFN hidden
    float*  x    = (float*)alloc((size_t)R * D * 4);
    float*  y    = (float*)alloc((size_t)R * D * 4);
    float*  side = (float*)alloc((size_t)B * 64 * S * 4); // row-sums per chunk slot
    __bf16* wqk_s = (__bf16*)alloc((size_t)2 * D * D * 2); // [Wq^T | Wk^T] (self)
    __bf16* wv_s  = (__bf16*)alloc((size_t)D * D * 2);
    __bf16* wv_c  = (__bf16*)alloc((size_t)D * D * 2);
    __bf16* wq_c  = (__bf16*)alloc((size_t)D * D * 2);
    __bf16* wk_c  = (__bf16*)alloc((size_t)D * D * 2);
    __bf16* W1t  = (__bf16*)alloc((size_t)Hp * D * 2);
    __bf16* W2t  = (__bf16*)alloc((size_t)D * Hp * 2);
    float*  b1p  = (float*)alloc((size_t)Hp * 4);

    const size_t PBb = (size_t)R * D * 2;                 // one bf16 partial (8MB)
    __bf16* pbuf = (__bf16*)alloc((size_t)4 * PBb);       // up to 4 partials
    if (off > ws_size) return;                            // workspace too small
    const long PBe = (long)R * D;                         // partial stride (elements)

    __bf16* xbf = bfA;
    __bf16* ybf = bfC;

    const dim3 blk(256);
    const dim3 blk512(512);

    auto launch_ln = [&](int np, const float* res, const float* sd, int lim,
                         const float* bias, float* of, __bf16* ob) {
        if (np == 4)      ln_res<4><<<R / 4, blk, 0, stream>>>(pbuf, PBe, res, sd, lim, bias, gamma, beta, of, ob);
        else if (np == 2) ln_res<2><<<R / 4, blk, 0, stream>>>(pbuf, PBe, res, sd, lim, bias, gamma, beta, of, ob);
        else              ln_res<1><<<R / 4, blk, 0, stream>>>(pbuf, PBe, res, sd, lim, bias, gamma, beta, of, ob);
    };

    // --- prep (single consolidated dispatch) ---
    prep_all<<<10754, blk, 0, stream>>>((const float4*)inputs, (const float4*)ctx,
        (bf16x4*)bfA, (bf16x4*)bfC, sa_Wq, sa_Wk, sa_Wv, ca_Wq, ca_Wk, ca_Wv, W1, W2,
        wqk_s, wv_s, wq_c, wk_c, wv_c, W1t, W2t, b1, b1p);

    // --- self QK projection ([Q|K] = bfA x [Wq^T|Wk^T]) ---
    gemm_nt<4><<<dim3(4, 128, 1), blk, 0, stream>>>(bfA, wqk_s, nullptr,
        Qb, Kb, nullptr, 2 * D, D, D, 0, 0, 0, 4, D, 0);
    // --- BOTH V^T upfront (z=0: self from bfA, z=1: cross from bfC) ---
    gemm_nt<1><<<dim3(128, 2, 2), blk, 0, stream>>>(wv_s, bfA, nullptr,
        Vt, nullptr, nullptr, R, D, D, (long)D * D, (long)R * D, (long)D * R, 128, D, 0);

    // --- self-attention (causal, fused) ---
    fattn<1><<<dim3(64, NSc, B), blk512, 0, stream>>>(Qb, Kb, Vt, pbuf, side, NSc, PBe, SCALE);
    launch_ln(NSc, inputs, side, NSc, nullptr, x, xbf);

    // --- cross Q,K projections in one dispatch (z=0: Q=xbf*Wq, z=1: K=bfC*Wk) ---
    gemm_nt<1><<<dim3(2, 128, 2), blk, 0, stream>>>(xbf, wq_c, nullptr,
        Qb, nullptr, nullptr, D, D, D, (long)R * D, (long)D * D, (long)R * D, 2, D, 0);

    // --- cross-attention (full, fused) ---
    fattn<0><<<dim3(64, NSx, B), blk512, 0, stream>>>(Qb, Kb, Vt + (size_t)D * R,
        pbuf, side, NSx, PBe, SCALE);
    launch_ln(NSx, x, side, NSx, nullptr, y, ybf);

    // --- FFN ---
    gemm_nt<2><<<dim3(4, 128, 1), blk, 0, stream>>>(ybf, W1t, b1p,
        h, nullptr, nullptr, Hp, D, D, 0, 0, 0, 4, D, 0);
    gemm_nt<3><<<dim3(2 * NSf, 128, 1), blk, 0, stream>>>(h, W2t, nullptr,
        pbuf, nullptr, nullptr, D, Hp, Hp, 0, 0, 0, 2, Hp / NSf, (long)PBb);
    launch_ln(NSf, y, nullptr, 0, b2, out, nullptr);   // b2 folded into pre-LN sum
}